// Round 5
// baseline (359.751 us; speedup 1.0000x reference)
//
#include <hip/hip_runtime.h>
#include <stdint.h>

typedef __attribute__((ext_vector_type(8))) __bf16 bf16x8;
typedef __attribute__((ext_vector_type(4))) float f32x4;
typedef __attribute__((ext_vector_type(16))) float f32x16;
typedef __attribute__((ext_vector_type(4))) short short4v;
typedef __attribute__((ext_vector_type(4))) unsigned uint4v;

// Problem constants
static constexpr int SEQ  = 2048;   // N
static constexpr int DQKV = 3072;   // q(2048) + k(512) + v(512)
static constexpr int HD   = 128;

// round-to-nearest-even fp32 -> bf16 bits
__device__ __forceinline__ short f2bf(float f) {
  unsigned u = __builtin_bit_cast(unsigned, f);
  u += 0x7fffu + ((u >> 16) & 1u);
  return (short)(u >> 16);
}

__device__ __forceinline__ unsigned pack2(float a, float b) {
  return (unsigned)(unsigned short)f2bf(a) | ((unsigned)(unsigned short)f2bf(b) << 16);
}

// async global->LDS, 16B per lane; LDS dest must be wave-uniform base + lane*16
__device__ __forceinline__ void gl_lds16(const void* g, void* l) {
  __builtin_amdgcn_global_load_lds(
      (const __attribute__((address_space(1))) void*)g,
      (__attribute__((address_space(3))) void*)l, 16, 0, 0);
}

// ---------------- fused prep: cast x + transpose-cast all weights ----------------
__global__ __launch_bounds__(256)
void prep_kernel(const float* __restrict__ x, const float* __restrict__ Wq,
                 const float* __restrict__ Wk, const float* __restrict__ Wv,
                 const float* __restrict__ Wo,
                 short* __restrict__ xb, short* __restrict__ WqkvT,
                 short* __restrict__ WoT) {
  int blk = blockIdx.x, tid = threadIdx.x;
  if (blk < 8192) {
    int i = blk * 256 + tid;
    float4 v = reinterpret_cast<const float4*>(x)[i];
    short4v o;
    o[0] = f2bf(v.x); o[1] = f2bf(v.y); o[2] = f2bf(v.z); o[3] = f2bf(v.w);
    *reinterpret_cast<short4v*>(xb + (size_t)i * 4) = o;
    return;
  }
  blk -= 8192;
  __shared__ float tile[32][33];
  const float* in; short* out; int C, bx, by;
  if (blk < 4096)      { in = Wq; out = WqkvT;                     C = 2048; bx = blk & 63; by = blk >> 6; }
  else if (blk < 5120) { int t = blk - 4096; in = Wk; out = WqkvT + (size_t)2048 * 2048; C = 512; bx = t & 15; by = t >> 4; }
  else if (blk < 6144) { int t = blk - 5120; in = Wv; out = WqkvT + (size_t)2560 * 2048; C = 512; bx = t & 15; by = t >> 4; }
  else                 { int t = blk - 6144; in = Wo; out = WoT;   C = 2048; bx = t & 63; by = t >> 6; }
  const int R = 2048;
  int c0 = bx * 32, r0 = by * 32, tx = tid & 31, ty = tid >> 5;
  for (int i = 0; i < 4; i++)
    tile[ty + i * 8][tx] = in[(size_t)(r0 + ty + i * 8) * C + c0 + tx];
  __syncthreads();
  for (int i = 0; i < 4; i++)
    out[(size_t)(c0 + ty + i * 8) * R + r0 + tx] = f2bf(tile[tx][ty + i * 8]);
}

// -------- transpose V section of qkv[4096][3072] -> vT[b*512 + gd][2048] bf16 --------
__global__ __launch_bounds__(256) void transpose_v_kernel(const short* __restrict__ qkv,
                                                          short* __restrict__ vT) {
  __shared__ short tile[32][33];
  int n0 = blockIdx.x * 32, c0 = blockIdx.y * 32, b = blockIdx.z;
  int tx = threadIdx.x & 31, ty = threadIdx.x >> 5;
  for (int i = 0; i < 4; i++)
    tile[ty + i * 8][tx] = qkv[(size_t)(b * SEQ + n0 + ty + i * 8) * DQKV + 2560 + c0 + tx];
  __syncthreads();
  for (int i = 0; i < 4; i++)
    vT[(size_t)(b * 512 + c0 + ty + i * 8) * SEQ + n0 + tx] = tile[tx][ty + i * 8];
}

// ---------------- bf16 GEMM, BK=64: C[M][N] = A[M][K] @ BT[N][K]^T ----------------
// 128x128 macro-tile, BK=64 in two 32-k slabs (32KB LDS) -> 3 blocks/CU.
// Round-4 lesson: do NOT scatter the epilogue (pre-swizzling K cols broke store
// coalescing, +15us). Plain contiguous stores restored.
template <int F32OUT>
__global__ __launch_bounds__(256)
void gemm_bt_kernel(const short* __restrict__ A, const short* __restrict__ BT,
                    void* __restrict__ Cout, const float* __restrict__ bias,
                    int M, int N, int K, int qcols, float qscale) {
  __shared__ __align__(16) short As[8192];  // 2 kslabs x [128 rows][32 k]
  __shared__ __align__(16) short Bs[8192];
  const int tid = threadIdx.x, lane = tid & 63, w = tid >> 6;
  const int l15 = lane & 15, quad = lane >> 4, q8 = quad * 8;
  const int row0 = blockIdx.y * 128, col0 = blockIdx.x * 128;
  const int wm = (w >> 1) * 64, wn = (w & 1) * 64;
  f32x4 acc[4][4] = {};
  const short* ga0 = A  + (size_t)(row0 + w * 16 + (lane >> 2)) * K + (lane & 3) * 8;
  const short* gb0 = BT + (size_t)(col0 + w * 16 + (lane >> 2)) * K + (lane & 3) * 8;
  for (int kt = 0; kt < K; kt += 64) {
    for (int s = 0; s < 2; s++) {
      gl_lds16(ga0 + kt + s * 32,                  As + s * 4096 + w * 512);
      gl_lds16(ga0 + (size_t)64 * K + kt + s * 32, As + s * 4096 + 2048 + w * 512);
      gl_lds16(gb0 + kt + s * 32,                  Bs + s * 4096 + w * 512);
      gl_lds16(gb0 + (size_t)64 * K + kt + s * 32, Bs + s * 4096 + 2048 + w * 512);
    }
    __syncthreads();  // drains vmcnt -> staged tiles visible
    for (int s = 0; s < 2; s++) {
      bf16x8 af[4], bfr[4];
      for (int i = 0; i < 4; i++)
        af[i] = *reinterpret_cast<const bf16x8*>(As + s * 4096 + (wm + i * 16 + l15) * 32 + q8);
      for (int j = 0; j < 4; j++)
        bfr[j] = *reinterpret_cast<const bf16x8*>(Bs + s * 4096 + (wn + j * 16 + l15) * 32 + q8);
      for (int i = 0; i < 4; i++)
        for (int j = 0; j < 4; j++)
          acc[i][j] = __builtin_amdgcn_mfma_f32_16x16x32_bf16(af[i], bfr[j], acc[i][j], 0, 0, 0);
    }
    __syncthreads();  // protect LDS reuse next iteration
  }
  if (F32OUT) {
    float* C = (float*)Cout;
    for (int j = 0; j < 4; j++) {
      int col = col0 + wn + j * 16 + l15;
      float bv = bias[col];
      for (int i = 0; i < 4; i++)
        for (int r = 0; r < 4; r++)
          C[(size_t)(row0 + wm + i * 16 + quad * 4 + r) * N + col] = acc[i][j][r] + bv;
    }
  } else {
    short* C = (short*)Cout;
    for (int j = 0; j < 4; j++) {
      int col = col0 + wn + j * 16 + l15;
      float sc = (col < qcols) ? qscale : 1.0f;
      for (int i = 0; i < 4; i++)
        for (int r = 0; r < 4; r++)
          C[(size_t)(row0 + wm + i * 16 + quad * 4 + r) * N + col] = f2bf(acc[i][j][r] * sc);
    }
  }
}

// ---------------- flash attention, causal, GQA — v5: 1-deep pipeline --------------
// v3 profile: wall 5236 cy/iter; VALU 39% (softmax chain), LDS ~44%, MFMA ~5% —
// latency-bound on the per-iteration S->softmax->PV dependency chain at 2
// waves/SIMD (occupancy hard-capped: LDS 74KB, grid 512 = 2 blocks/CU).
// v5 overlaps softmax/PV of tile t-1 with S-MFMA + V-capture of tile t (ILP):
//   window t: barrier; stage(t+1); PH1(t)={S-mfma from Ks[t&1], V->regs from
//   Vs[t&1]}; PH2(t-1)={mask, v_exp, pack, permlane, PV(from captured V regs),
//   epilogue}.  Ping-pong register sets A/B via macros (static indexing).
// Buffer lifetime: stage(t+1) overwrites buf[(t+1)&1], last read by PH1(t-1)
// before this barrier; PV(t-1) reads only registers. total==33 uniform -> exact
// 2x-unrolled loop, no register copies. exp2f -> raw v_exp_f32. VGPR ~200 is
// free (LDS-capped occupancy).
__global__ __launch_bounds__(256, 2)
void attn_kernel(const short* __restrict__ qkv, const short* __restrict__ vT,
                 short* __restrict__ ctx) {
  __shared__ __align__(16) short Ks[2 * 8192];  // dbuf x [64 k][16 chunks], swizzled
  __shared__ __align__(16) short Vs[2 * 8192];  // dbuf x [128 d][8 chunks], swizzled
  __shared__ __align__(16) float Oex[2048];     // 8KB: per-dt O^T exchange (4 passes)
  __shared__ float lbuf[4 * 32];                // per-wave khalf-partial l
  const int tid = threadIdx.x, lane = tid & 63, w = tid >> 6;
  const int l31 = lane & 31, hi = lane >> 5;
  const int qh = w & 1, kh = w >> 1;
  const int idx = blockIdx.x;
  const int p = idx >> 5, h = (idx >> 1) & 15, b = idx & 1, g = h >> 2;
  const int qtA = 31 - p, qtB = p;
  const int lenA = qtA + 1;                      // total iterations == 33 for every block

  auto stage = [&](int buf, int kt) {
    const short* gk = qkv + (size_t)(b * SEQ + kt * 64) * DQKV + 2048 + g * HD;
#pragma unroll
    for (int s = 0; s < 4; s++) {
      const int r = w * 16 + s * 4 + (lane >> 4);  // k row; 16 chunks/row
      gl_lds16(gk + (size_t)r * DQKV + ((lane & 15) ^ (r & 7)) * 8,
               Ks + buf * 8192 + (w * 16 + s * 4) * 128);
    }
    const short* gv = vT + (size_t)(b * 512 + g * HD) * SEQ + kt * 64;
#pragma unroll
    for (int s = 0; s < 4; s++) {
      const int r = w * 32 + s * 8 + (lane >> 3);  // d row; 8 chunks/row
      gl_lds16(gv + (size_t)r * SEQ + ((lane & 7) ^ (r & 7)) * 8,
               Vs + buf * 8192 + (w * 32 + s * 8) * 64);
    }
  };

  bf16x8 qf[8];          // Q^T fragments for current segment (32 q rows per wave)
  f32x16 o_acc[4] = {};  // O^T[d = dt*32 + crow][q = l31], own k-half only
  float lsum = 0.f;      // running sum of P over (own khalf, own hi-subset) per q=l31
  f32x16 saA, saB;       // pipelined S tiles (ping-pong)
  bf16x8 vfA[4][2], vfB[4][2];  // pipelined V fragment captures (ping-pong)

  auto loadQ = [&](int qt) {
    const short* gq = qkv + (size_t)(b * SEQ + qt * 64 + qh * 32 + l31) * DQKV + h * HD + hi * 8;
#pragma unroll
    for (int d = 0; d < 8; d++) qf[d] = *reinterpret_cast<const bf16x8*>(gq + d * 16);
  };

// PH1(t): S^T = K(khalf)@Q(qhalf)^T from Ks[CUR]; capture V frags from Vs[CUR].
#define PH1_BODY(T, CUR, SA, VF)                                                   \
  {                                                                                \
    if ((T) == 0 || (T) == lenA) loadQ(((T) >= lenA) ? qtB : qtA);                 \
    const short* Kb_ = Ks + (CUR) * 8192;                                          \
    const short* Vb_ = Vs + (CUR) * 8192;                                          \
    f32x16 s0_ = {}, s1_ = {};                                                     \
    __builtin_amdgcn_s_setprio(1);                                                 \
    _Pragma("unroll")                                                              \
    for (int d_ = 0; d_ < 4; d_++) {                                               \
      bf16x8 kf0_ = *reinterpret_cast<const bf16x8*>(                              \
          Kb_ + (kh * 32 + l31) * 128 + (((2 * d_ + hi) ^ (l31 & 7)) * 8));        \
      bf16x8 kf1_ = *reinterpret_cast<const bf16x8*>(                              \
          Kb_ + (kh * 32 + l31) * 128 + (((2 * (d_ + 4) + hi) ^ (l31 & 7)) * 8));  \
      s0_ = __builtin_amdgcn_mfma_f32_32x32x16_bf16(kf0_, qf[d_], s0_, 0, 0, 0);   \
      s1_ = __builtin_amdgcn_mfma_f32_32x32x16_bf16(kf1_, qf[d_ + 4], s1_, 0, 0, 0);\
    }                                                                              \
    __builtin_amdgcn_s_setprio(0);                                                 \
    SA = s0_ + s1_;                                                                \
    _Pragma("unroll")                                                              \
    for (int dt_ = 0; dt_ < 4; dt_++)                                              \
      _Pragma("unroll")                                                            \
      for (int sub_ = 0; sub_ < 2; sub_++) {                                       \
        const int kc_ = kh * 4 + sub_ * 2 + hi;                                    \
        VF[dt_][sub_] = *reinterpret_cast<const bf16x8*>(                          \
            Vb_ + (dt_ * 32 + l31) * 64 + ((kc_ ^ (l31 & 7)) * 8));                \
      }                                                                            \
  }

// PH2(t): mask(diag) -> P=2^S -> pack+permlane -> PV from captured V -> epilogue.
#define PH2_BODY(T, SA, VF)                                                        \
  {                                                                                \
    const int seg_ = ((T) >= lenA);                                                \
    const int ktc_ = seg_ ? (T) - lenA : (T);                                      \
    const int qtc_ = seg_ ? qtB : qtA;                                             \
    const bool diag_ = (ktc_ == qtc_);                                             \
    if (diag_) {                                                                   \
      const int q_ = qh * 32 + l31;                                                \
      _Pragma("unroll")                                                            \
      for (int r_ = 0; r_ < 16; r_++)                                              \
        if (kh * 32 + (r_ & 3) + 8 * (r_ >> 2) + 4 * hi > q_) SA[r_] = -1e38f;     \
    }                                                                              \
    float ps_[16];                                                                 \
    _Pragma("unroll")                                                              \
    for (int r_ = 0; r_ < 16; r_++)                                                \
      asm("v_exp_f32 %0, %1" : "=v"(ps_[r_]) : "v"(SA[r_]));                       \
    _Pragma("unroll")                                                              \
    for (int r_ = 0; r_ < 16; r_++) lsum += ps_[r_];                               \
    unsigned ub_[4][2];                                                            \
    _Pragma("unroll")                                                              \
    for (int j_ = 0; j_ < 4; j_++) {                                               \
      unsigned a0_ = __builtin_bit_cast(unsigned, ps_[4 * j_ + 0]);                \
      unsigned a1_ = __builtin_bit_cast(unsigned, ps_[4 * j_ + 1]);                \
      unsigned a2_ = __builtin_bit_cast(unsigned, ps_[4 * j_ + 2]);                \
      unsigned a3_ = __builtin_bit_cast(unsigned, ps_[4 * j_ + 3]);                \
      ub_[j_][0] = (a0_ >> 16) | (a1_ & 0xffff0000u);                              \
      ub_[j_][1] = (a2_ >> 16) | (a3_ & 0xffff0000u);                              \
    }                                                                              \
    bf16x8 pf_[2];                                                                 \
    _Pragma("unroll")                                                              \
    for (int sub_ = 0; sub_ < 2; sub_++) {                                         \
      auto s0_ = __builtin_amdgcn_permlane32_swap((int)ub_[2 * sub_][0],           \
                                                  (int)ub_[2 * sub_ + 1][0], false, false); \
      auto s1_ = __builtin_amdgcn_permlane32_swap((int)ub_[2 * sub_][1],           \
                                                  (int)ub_[2 * sub_ + 1][1], false, false); \
      uint4v uu_;                                                                  \
      uu_[0] = (unsigned)s0_[0]; uu_[1] = (unsigned)s1_[0];                        \
      uu_[2] = (unsigned)s0_[1]; uu_[3] = (unsigned)s1_[1];                        \
      pf_[sub_] = __builtin_bit_cast(bf16x8, uu_);                                 \
    }                                                                              \
    __builtin_amdgcn_s_setprio(1);                                                 \
    _Pragma("unroll")                                                              \
    for (int dt_ = 0; dt_ < 4; dt_++)                                              \
      _Pragma("unroll")                                                            \
      for (int sub_ = 0; sub_ < 2; sub_++)                                         \
        o_acc[dt_] = __builtin_amdgcn_mfma_f32_32x32x16_bf16(VF[dt_][sub_], pf_[sub_], \
                                                             o_acc[dt_], 0, 0, 0); \
    __builtin_amdgcn_s_setprio(0);                                                 \
    if (diag_) {                                                                   \
      float lp_ = lsum + __shfl_xor(lsum, 32, 64);                                 \
      if (lane < 32) lbuf[w * 32 + l31] = lp_;                                     \
      float invl_ = 0.f;                                                           \
      const size_t row_ = (size_t)(b * SEQ + qtc_ * 64 + qh * 32 + l31);           \
      _Pragma("unroll")                                                            \
      for (int dt_ = 0; dt_ < 4; dt_++) {                                          \
        if (w >= 2) {                                                              \
          float* oex_ = Oex + (w - 2) * 1024;                                      \
          _Pragma("unroll")                                                        \
          for (int rq_ = 0; rq_ < 4; rq_++) {                                      \
            f32x4 vv_ = {o_acc[dt_][4 * rq_ + 0], o_acc[dt_][4 * rq_ + 1],         \
                         o_acc[dt_][4 * rq_ + 2], o_acc[dt_][4 * rq_ + 3]};        \
            *reinterpret_cast<f32x4*>(oex_ + (rq_ * 64 + lane) * 4) = vv_;         \
          }                                                                        \
        }                                                                          \
        __syncthreads();                                                           \
        if (w < 2) {                                                               \
          if (dt_ == 0) invl_ = 1.f / (lp_ + lbuf[(w ^ 2) * 32 + l31]);            \
          const float* oex_ = Oex + w * 1024;                                      \
          _Pragma("unroll")                                                        \
          for (int rq_ = 0; rq_ < 4; rq_++) {                                      \
            f32x4 vv_ = *reinterpret_cast<const f32x4*>(oex_ + (rq_ * 64 + lane) * 4); \
            float e0_ = (o_acc[dt_][4 * rq_ + 0] + vv_[0]) * invl_;                \
            float e1_ = (o_acc[dt_][4 * rq_ + 1] + vv_[1]) * invl_;                \
            float e2_ = (o_acc[dt_][4 * rq_ + 2] + vv_[2]) * invl_;                \
            float e3_ = (o_acc[dt_][4 * rq_ + 3] + vv_[3]) * invl_;                \
            uint2 dd_ = make_uint2(pack2(e0_, e1_), pack2(e2_, e3_));              \
            *reinterpret_cast<uint2*>(ctx + row_ * 2048 + h * HD + dt_ * 32 +      \
                                      rq_ * 8 + hi * 4) = dd_;                     \
          }                                                                        \
        }                                                                          \
        __syncthreads();                                                           \
      }                                                                            \
      _Pragma("unroll")                                                            \
      for (int dt_ = 0; dt_ < 4; dt_++)                                            \
        _Pragma("unroll")                                                          \
        for (int e_ = 0; e_ < 16; e_++) o_acc[dt_][e_] = 0.f;                      \
      lsum = 0.f;                                                                  \
    }                                                                              \
  }

  // ---- prologue: t = 0 ----
  stage(0, 0);
  __syncthreads();                       // buf0 staged
  stage(1, (1 >= lenA) ? 1 - lenA : 1);  // lenA >= 17, so kt = 1
  __builtin_amdgcn_sched_barrier(0);
  PH1_BODY(0, 0, saA, vfA)

  // ---- steady state: t = 1..32, two windows per loop iteration ----
  for (int tb = 1; tb <= 31; tb += 2) {
    // window t = tb (odd, reads buf1)
    __syncthreads();
    { const int tn = tb + 1; stage(0, (tn >= lenA) ? tn - lenA : tn); }
    __builtin_amdgcn_sched_barrier(0);
    PH1_BODY(tb, 1, saB, vfB)
    PH2_BODY(tb - 1, saA, vfA)
    // window t = tb+1 (even, reads buf0)
    __syncthreads();
    if (tb + 2 < 33) { const int tn = tb + 2; stage(1, (tn >= lenA) ? tn - lenA : tn); }
    __builtin_amdgcn_sched_barrier(0);
    PH1_BODY(tb + 1, 0, saA, vfA)
    PH2_BODY(tb, saB, vfB)
  }
  // ---- drain: finish tile 32 (diagonal of segment B -> epilogue) ----
  PH2_BODY(32, saA, vfA)

#undef PH1_BODY
#undef PH2_BODY
}

extern "C" void kernel_launch(void* const* d_in, const int* in_sizes, int n_in,
                              void* d_out, int out_size, void* d_ws, size_t ws_size,
                              hipStream_t stream) {
  const float* x  = (const float*)d_in[0];
  const float* Wq = (const float*)d_in[1];
  const float* Wk = (const float*)d_in[2];
  const float* Wv = (const float*)d_in[3];
  const float* Wo = (const float*)d_in[4];
  const float* bo = (const float*)d_in[5];
  float* out = (float*)d_out;

  // softmax scale folded into Q: (1/sqrt(128)) * log2(e)
  const float sc2 = 0.08838834764831845f * 1.4426950408889634f;

  // workspace layout (bf16 as short), total ~84 MB
  short* xb    = (short*)d_ws;                   // [4096][2048]
  short* WqkvT = xb    + (size_t)4096 * 2048;    // [3072][2048]  rows: WqT | WkT | WvT
  short* WoT   = WqkvT + (size_t)3072 * 2048;    // [2048][2048]
  short* qkv   = WoT   + (size_t)2048 * 2048;    // [4096][3072]
  short* vT    = qkv   + (size_t)4096 * 3072;    // [2*512][2048]
  short* ctx   = vT    + (size_t)1024 * 2048;    // [4096][2048]

  prep_kernel<<<dim3(18432), dim3(256), 0, stream>>>(x, Wq, Wk, Wv, Wo, xb, WqkvT, WoT);
  // qkv = xb @ WqkvT^T : M=4096, N=3072, K=2048; q cols pre-scaled by sc2
  gemm_bt_kernel<0><<<dim3(24, 32), dim3(256), 0, stream>>>(xb, WqkvT, qkv, nullptr,
                                                            4096, 3072, 2048, 2048, sc2);
  transpose_v_kernel<<<dim3(64, 16, 2), dim3(256), 0, stream>>>(qkv, vT);
  attn_kernel<<<dim3(512), dim3(256), 0, stream>>>(qkv, vT, ctx);
  // out = ctx @ WoT^T + bo : M=4096, N=2048, K=2048, fp32 epilogue
  gemm_bt_kernel<1><<<dim3(16, 32), dim3(256), 0, stream>>>(ctx, WoT, out, bo,
                                                            4096, 2048, 2048, 0, 1.0f);
}